// Round 5
// baseline (130.448 us; speedup 1.0000x reference)
//
#include <hip/hip_runtime.h>
#include <hip/hip_bf16.h>
#include <hip/hip_cooperative_groups.h>
#include <math.h>

namespace cg = cooperative_groups;

// Problem constants (from reference)
#define B_   64
#define C_   256
#define H_   56
#define W_   56
#define L_   8
#define OUT_ 4096
#define KDIM 2048

typedef __attribute__((ext_vector_type(8))) short short8v;   // 8 bf16 (4 VGPRs)
typedef __attribute__((ext_vector_type(4))) float float4v;   // MFMA C/D

// 8-byte value with only 4-byte alignment guarantee (x0 can be odd).
struct __attribute__((packed, aligned(4))) F2 { float x, y; };

// fp32 -> bf16 bits, RNE
__device__ __forceinline__ unsigned short f2bf(float f) {
    unsigned u = __builtin_bit_cast(unsigned, f);
    return (unsigned short)((u + 0x7fffu + ((u >> 16) & 1u)) >> 16);
}

// ---------------------------------------------------------------------------
// Fused cooperative kernel. 256 blocks x 512 threads, 1 block/CU.
// Phase A: each block (a) computes 2 ROIs (512 total) -> pooled bf16 global,
//          (b) streams its 16 W rows fp32->bf16 into a swizzled LDS tile.
//          Both HBM streams (scatter + stream) overlap.
// grid sync.
// Phase B: MFMA GEMM: A (pooled, 256KB, L2/L3) x W^T (LDS) -> bias+relu->out.
// LDS: 64KB union { bf16 Wlds[16][2048] (XOR-swizzled) ; f32 red[8][64][16] }.
// ---------------------------------------------------------------------------
__global__ __launch_bounds__(512, 1) void fused_kernel(
    const float* __restrict__ feat,          // (64,256,56,56)
    const float* __restrict__ lms,           // (64,16)
    const float* __restrict__ Wl,            // (4096,2048) fp32
    const float* __restrict__ bl,            // (4096)
    unsigned short* __restrict__ pooled,     // ws: (64,2048) bf16 bits
    float* __restrict__ out)                 // (64,4096) fp32
{
    __shared__ unsigned char smem[65536];

    const int t   = threadIdx.x;
    const int bid = blockIdx.x;
    const int n0  = bid * 16;

    // ================= Phase A =================
    // ---- ROI job: XCD-affine mapping (block j -> XCD j%8), all 8 landmarks
    // of a batch on one XCD for L2 row dedupe. 2 rois/block, 256 ch each.
    {
        const int xcd  = bid & 7;
        const int slot = bid >> 3;                    // 0..31
        const int roi  = xcd * 64 + slot * 2 + (t >> 8);  // 0..511
        const int b = roi >> 3;
        const int l = roi & 7;
        const int c = t & 255;

        const float lx = lms[b * (L_ * 2) + 2 * l];
        const float ly = lms[b * (L_ * 2) + 2 * l + 1];
        const float tx = -1.0f + lx * (1.0f / 112.0f);
        const float ty = -1.0f + ly * (1.0f / 112.0f);
        const float Aaff = 2.0f / 7.0f;

        float wx[2]; int xb[2]; bool xhi[2];
        #pragma unroll
        for (int j = 0; j < 2; ++j) {
            const float base = (j == 0) ? -0.5f : 0.5f;
            const float gx = Aaff * base + tx;
            float fx = ((gx + 1.0f) * (float)W_ - 1.0f) * 0.5f;
            fx = fminf(fmaxf(fx, 0.0f), (float)(W_ - 1));
            const float fx0 = floorf(fx);
            wx[j] = fx - fx0;
            const int x0 = (int)fx0;
            xhi[j] = (x0 == W_ - 1);          // clamped: wx==0
            xb[j]  = xhi[j] ? (W_ - 2) : x0;  // packed 8B load base, in-row
        }
        float wy[2]; int y0[2], y1[2];
        #pragma unroll
        for (int i = 0; i < 2; ++i) {
            const float base = (i == 0) ? -0.5f : 0.5f;
            const float gy = Aaff * base + ty;
            float fy = ((gy + 1.0f) * (float)H_ - 1.0f) * 0.5f;
            fy = fminf(fmaxf(fy, 0.0f), (float)(H_ - 1));
            const float fy0 = floorf(fy);
            wy[i] = fy - fy0;
            y0[i] = (int)fy0;
            y1[i] = min(y0[i] + 1, H_ - 1);
        }

        const float* fb = feat + ((size_t)(b * C_ + c)) * (H_ * W_);
        // 8 independent packed loads (2 y-samples x 2 x-windows x 2 rows)
        F2 p[2][2][2];   // [iy][row01][jx]
        #pragma unroll
        for (int i = 0; i < 2; ++i) {
            const float* r0 = fb + y0[i] * W_;
            const float* r1 = fb + y1[i] * W_;
            #pragma unroll
            for (int j = 0; j < 2; ++j) {
                p[i][0][j] = *(const F2*)(r0 + xb[j]);
                p[i][1][j] = *(const F2*)(r1 + xb[j]);
            }
        }
        float mx = -INFINITY;
        #pragma unroll
        for (int i = 0; i < 2; ++i) {
            #pragma unroll
            for (int j = 0; j < 2; ++j) {
                const float v00 = xhi[j] ? p[i][0][j].y : p[i][0][j].x;
                const float v10 = xhi[j] ? p[i][1][j].y : p[i][1][j].x;
                const float top = v00 + wx[j] * (p[i][0][j].y - v00);
                const float bot = v10 + wx[j] * (p[i][1][j].y - v10);
                const float val = top + wy[i] * (bot - top);
                mx = fmaxf(mx, val);
            }
        }
        pooled[roi * 256 + c] = f2bf(mx);
    }

    // ---- W staging: 16 rows x 2048 fp32 -> bf16 LDS, XOR-swizzled.
    // 8 iters x (2 float4 loads -> 16B ds_write). row = 2i + (t>>8), s = t&255.
    {
        #pragma unroll
        for (int i = 0; i < 8; ++i) {
            const int row = 2 * i + (t >> 8);     // 0..15
            const int s   = t & 255;              // 16B segment within row
            const float* src = Wl + (size_t)(n0 + row) * KDIM + s * 8;
            const float4 g0 = *(const float4*)src;
            const float4 g1 = *(const float4*)(src + 4);
            unsigned short h[8];
            h[0] = __builtin_bit_cast(unsigned short, (__bf16)g0.x);
            h[1] = __builtin_bit_cast(unsigned short, (__bf16)g0.y);
            h[2] = __builtin_bit_cast(unsigned short, (__bf16)g0.z);
            h[3] = __builtin_bit_cast(unsigned short, (__bf16)g0.w);
            h[4] = __builtin_bit_cast(unsigned short, (__bf16)g1.x);
            h[5] = __builtin_bit_cast(unsigned short, (__bf16)g1.y);
            h[6] = __builtin_bit_cast(unsigned short, (__bf16)g1.z);
            h[7] = __builtin_bit_cast(unsigned short, (__bf16)g1.w);
            const int kbyte = (s * 16) ^ ((row & 7) << 4);   // T2 swizzle
            *(short8v*)&smem[row * 4096 + kbyte] = *(const short8v*)h;
        }
    }

    __threadfence();          // release pooled to device scope
    cg::this_grid().sync();   // all pooled + all LDS tiles ready

    // ================= Phase B: MFMA GEMM =================
    const int lane = t & 63;
    const int wv   = t >> 6;            // k-eighth 0..7
    const int rs   = lane & 15;         // A-row / W-row within fragment
    const int oct  = lane >> 4;         // k-octet (8 contiguous k)

    float4v acc[4];
    #pragma unroll
    for (int mt = 0; mt < 4; ++mt) acc[mt] = (float4v){0.f, 0.f, 0.f, 0.f};

    const int kq0 = wv * (KDIM / 8);    // 256 k per wave

    #pragma unroll 4
    for (int ks = 0; ks < 8; ++ks) {
        const int koff = kq0 + ks * 32 + oct * 8;
        const int kbyte = (koff * 2) ^ ((rs & 7) << 4);
        const short8v bfrag = *(const short8v*)&smem[rs * 4096 + kbyte];
        #pragma unroll
        for (int mt = 0; mt < 4; ++mt) {
            const short8v afrag =
                *(const short8v*)((const short*)pooled + (size_t)(mt * 16 + rs) * KDIM + koff);
            acc[mt] = __builtin_amdgcn_mfma_f32_16x16x32_bf16(afrag, bfrag, acc[mt], 0, 0, 0);
        }
    }

    __syncthreads();   // all waves done reading Wlds before red overwrites it
    float (*red)[64][16] = (float (*)[64][16])smem;   // 32 KB
    #pragma unroll
    for (int mt = 0; mt < 4; ++mt)
        #pragma unroll
        for (int r = 0; r < 4; ++r)
            red[wv][mt * 16 + oct * 4 + r][rs] = acc[mt][r];
    __syncthreads();

    #pragma unroll
    for (int i = 0; i < 2; ++i) {
        const int idx = t + i * 512;
        const int m = idx >> 4;
        const int n = idx & 15;
        float s = 0.0f;
        #pragma unroll
        for (int q = 0; q < 8; ++q) s += red[q][m][n];
        s += bl[n0 + n];
        out[(size_t)m * OUT_ + n0 + n] = s > 0.0f ? s : 0.0f;
    }
}

// ---------------------------------------------------------------------------
extern "C" void kernel_launch(void* const* d_in, const int* in_sizes, int n_in,
                              void* d_out, int out_size, void* d_ws, size_t ws_size,
                              hipStream_t stream) {
    const float* features  = (const float*)d_in[0];  // (64,256,56,56)
    const float* landmarks = (const float*)d_in[1];  // (64,16)
    const float* W_lin     = (const float*)d_in[2];  // (4096,2048)
    const float* b_lin     = (const float*)d_in[3];  // (4096,)
    float* out = (float*)d_out;                      // (64,4096)

    unsigned short* pooled = (unsigned short*)d_ws;  // (64,2048) bf16 = 256 KB

    void* args[] = {(void*)&features, (void*)&landmarks, (void*)&W_lin,
                    (void*)&b_lin, (void*)&pooled, (void*)&out};
    hipLaunchCooperativeKernel((void*)fused_kernel, dim3(256), dim3(512),
                               args, 0, stream);
}

// Round 6
// 67.856 us; speedup vs baseline: 1.9224x; 1.9224x over previous
//
#include <hip/hip_runtime.h>
#include <hip/hip_bf16.h>
#include <math.h>

// Problem constants (from reference)
#define B_   64
#define C_   256
#define H_   56
#define W_   56
#define L_   8
#define OUT_ 4096
#define KDIM 2048

typedef __attribute__((ext_vector_type(8))) short short8v;   // 8 bf16 (4 VGPRs)
typedef __attribute__((ext_vector_type(4))) float float4v;   // MFMA C/D

// 8-byte value with only 4-byte alignment guarantee (x0 can be odd).
struct __attribute__((packed, aligned(4))) F2 { float x, y; };

// fp32 -> bf16 bits, RNE
__device__ __forceinline__ unsigned short f2bf(float f) {
    unsigned u = __builtin_bit_cast(unsigned, f);
    return (unsigned short)((u + 0x7fffu + ((u >> 16) & 1u)) >> 16);
}

// ---------------------------------------------------------------------------
// Fused kernel, hand-rolled grid barrier (NO cooperative launch).
// 256 blocks x 512 threads = exactly 1 block/CU -> co-resident.
// Phase A: (a) 2 ROIs/block -> pooled bf16 (global), (b) 16 W rows fp32->bf16
//          into swizzled LDS. Both HBM streams overlap (scatter + stream).
// Barrier: arrival counter in d_ws (reset by hipMemsetAsync each call),
//          t0 releases + spins with s_sleep, agent-scope acquire.
// Phase B: MFMA GEMM A(pooled, L2) x W^T(LDS) + bias + relu -> out.
// ---------------------------------------------------------------------------
__global__ __launch_bounds__(512, 1) void fused_kernel(
    const float* __restrict__ feat,          // (64,256,56,56)
    const float* __restrict__ lms,           // (64,16)
    const float* __restrict__ Wl,            // (4096,2048) fp32
    const float* __restrict__ bl,            // (4096)
    unsigned short* __restrict__ pooled,     // ws: (64,2048) bf16 bits
    unsigned int* __restrict__ bar,          // ws: arrival counter (zeroed)
    float* __restrict__ out)                 // (64,4096) fp32
{
    __shared__ unsigned char smem[65536];

    const int t   = threadIdx.x;
    const int bid = blockIdx.x;
    const int n0  = bid * 16;

    // ================= Phase A =================
    // ---- W stream: issue all 16 float4 loads first (pure BW traffic).
    float4 wreg[16];
    {
        const int row0 = t >> 8;             // 0/1
        const int s    = t & 255;            // 32B segment within row
        #pragma unroll
        for (int i = 0; i < 8; ++i) {
            const int row = 2 * i + row0;
            const float* src = Wl + (size_t)(n0 + row) * KDIM + s * 8;
            wreg[2 * i]     = *(const float4*)src;
            wreg[2 * i + 1] = *(const float4*)(src + 4);
        }
    }

    // ---- ROI scatter (latency traffic, overlaps the W misses).
    {
        const int xcd  = bid & 7;
        const int slot = bid >> 3;                       // 0..31
        const int roi  = xcd * 64 + slot * 2 + (t >> 8); // 0..511
        const int b = roi >> 3;
        const int l = roi & 7;
        const int c = t & 255;

        const float lx = lms[b * (L_ * 2) + 2 * l];
        const float ly = lms[b * (L_ * 2) + 2 * l + 1];
        const float tx = -1.0f + lx * (1.0f / 112.0f);
        const float ty = -1.0f + ly * (1.0f / 112.0f);
        const float Aaff = 2.0f / 7.0f;

        float wx[2]; int xb[2]; bool xhi[2];
        #pragma unroll
        for (int j = 0; j < 2; ++j) {
            const float base = (j == 0) ? -0.5f : 0.5f;
            const float gx = Aaff * base + tx;
            float fx = ((gx + 1.0f) * (float)W_ - 1.0f) * 0.5f;
            fx = fminf(fmaxf(fx, 0.0f), (float)(W_ - 1));
            const float fx0 = floorf(fx);
            wx[j] = fx - fx0;
            const int x0 = (int)fx0;
            xhi[j] = (x0 == W_ - 1);          // clamped: wx==0
            xb[j]  = xhi[j] ? (W_ - 2) : x0;  // packed 8B load base, in-row
        }
        float wy[2]; int y0[2], y1[2];
        #pragma unroll
        for (int i = 0; i < 2; ++i) {
            const float base = (i == 0) ? -0.5f : 0.5f;
            const float gy = Aaff * base + ty;
            float fy = ((gy + 1.0f) * (float)H_ - 1.0f) * 0.5f;
            fy = fminf(fmaxf(fy, 0.0f), (float)(H_ - 1));
            const float fy0 = floorf(fy);
            wy[i] = fy - fy0;
            y0[i] = (int)fy0;
            y1[i] = min(y0[i] + 1, H_ - 1);
        }

        const float* fb = feat + ((size_t)(b * C_ + c)) * (H_ * W_);
        F2 p[2][2][2];   // [iy][row01][jx] -- 8 independent packed loads
        #pragma unroll
        for (int i = 0; i < 2; ++i) {
            const float* r0 = fb + y0[i] * W_;
            const float* r1 = fb + y1[i] * W_;
            #pragma unroll
            for (int j = 0; j < 2; ++j) {
                p[i][0][j] = *(const F2*)(r0 + xb[j]);
                p[i][1][j] = *(const F2*)(r1 + xb[j]);
            }
        }
        float mx = -INFINITY;
        #pragma unroll
        for (int i = 0; i < 2; ++i) {
            #pragma unroll
            for (int j = 0; j < 2; ++j) {
                const float v00 = xhi[j] ? p[i][0][j].y : p[i][0][j].x;
                const float v10 = xhi[j] ? p[i][1][j].y : p[i][1][j].x;
                const float top = v00 + wx[j] * (p[i][0][j].y - v00);
                const float bot = v10 + wx[j] * (p[i][1][j].y - v10);
                const float val = top + wy[i] * (bot - top);
                mx = fmaxf(mx, val);
            }
        }
        pooled[roi * 256 + c] = f2bf(mx);
    }

    // ---- Convert W regs -> bf16 swizzled LDS tile [16][2048].
    {
        const int row0 = t >> 8;
        const int s    = t & 255;
        #pragma unroll
        for (int i = 0; i < 8; ++i) {
            const int row = 2 * i + row0;
            const float4 g0 = wreg[2 * i];
            const float4 g1 = wreg[2 * i + 1];
            unsigned short h[8];
            h[0] = __builtin_bit_cast(unsigned short, (__bf16)g0.x);
            h[1] = __builtin_bit_cast(unsigned short, (__bf16)g0.y);
            h[2] = __builtin_bit_cast(unsigned short, (__bf16)g0.z);
            h[3] = __builtin_bit_cast(unsigned short, (__bf16)g0.w);
            h[4] = __builtin_bit_cast(unsigned short, (__bf16)g1.x);
            h[5] = __builtin_bit_cast(unsigned short, (__bf16)g1.y);
            h[6] = __builtin_bit_cast(unsigned short, (__bf16)g1.z);
            h[7] = __builtin_bit_cast(unsigned short, (__bf16)g1.w);
            const int kbyte = (s * 16) ^ ((row & 7) << 4);   // T2 swizzle
            *(short8v*)&smem[row * 4096 + kbyte] = *(const short8v*)h;
        }
    }

    // ================= Grid barrier (hand-rolled) =================
    __syncthreads();               // drains this block's vmem (pooled stores)
    if (t == 0) {
        // release: flush our pooled writes to device scope, then arrive
        __hip_atomic_fetch_add(bar, 1u, __ATOMIC_RELEASE, __HIP_MEMORY_SCOPE_AGENT);
        unsigned v;
        do {
            __builtin_amdgcn_s_sleep(8);
            v = __hip_atomic_load(bar, __ATOMIC_ACQUIRE, __HIP_MEMORY_SCOPE_AGENT);
        } while (v < 256u);        // acquire: invalidates L1/L2 for pooled reads
    }
    __syncthreads();

    // ================= Phase B: MFMA GEMM =================
    const int lane = t & 63;
    const int wv   = t >> 6;            // k-eighth 0..7
    const int rs   = lane & 15;         // A-row / W-row within fragment
    const int oct  = lane >> 4;         // k-octet (8 contiguous k)

    float4v acc[4];
    #pragma unroll
    for (int mt = 0; mt < 4; ++mt) acc[mt] = (float4v){0.f, 0.f, 0.f, 0.f};

    const int kq0 = wv * (KDIM / 8);    // 256 k per wave

    #pragma unroll 4
    for (int ks = 0; ks < 8; ++ks) {
        const int koff = kq0 + ks * 32 + oct * 8;
        const int kbyte = (koff * 2) ^ ((rs & 7) << 4);
        const short8v bfrag = *(const short8v*)&smem[rs * 4096 + kbyte];
        #pragma unroll
        for (int mt = 0; mt < 4; ++mt) {
            const short8v afrag =
                *(const short8v*)((const short*)pooled + (size_t)(mt * 16 + rs) * KDIM + koff);
            acc[mt] = __builtin_amdgcn_mfma_f32_16x16x32_bf16(afrag, bfrag, acc[mt], 0, 0, 0);
        }
    }

    __syncthreads();   // all waves done reading Wlds before red overwrites it
    float (*red)[64][16] = (float (*)[64][16])smem;   // 32 KB
    #pragma unroll
    for (int mt = 0; mt < 4; ++mt)
        #pragma unroll
        for (int r = 0; r < 4; ++r)
            red[wv][mt * 16 + oct * 4 + r][rs] = acc[mt][r];
    __syncthreads();

    #pragma unroll
    for (int i = 0; i < 2; ++i) {
        const int idx = t + i * 512;
        const int m = idx >> 4;
        const int n = idx & 15;
        float s = 0.0f;
        #pragma unroll
        for (int q = 0; q < 8; ++q) s += red[q][m][n];
        s += bl[n0 + n];
        out[(size_t)m * OUT_ + n0 + n] = s > 0.0f ? s : 0.0f;
    }
}

// ---------------------------------------------------------------------------
extern "C" void kernel_launch(void* const* d_in, const int* in_sizes, int n_in,
                              void* d_out, int out_size, void* d_ws, size_t ws_size,
                              hipStream_t stream) {
    const float* features  = (const float*)d_in[0];  // (64,256,56,56)
    const float* landmarks = (const float*)d_in[1];  // (64,16)
    const float* W_lin     = (const float*)d_in[2];  // (4096,2048)
    const float* b_lin     = (const float*)d_in[3];  // (4096,)
    float* out = (float*)d_out;                      // (64,4096)

    unsigned short* pooled = (unsigned short*)d_ws;                  // 256 KB
    unsigned int*   bar    = (unsigned int*)((char*)d_ws + 262144);  // counter

    hipMemsetAsync(bar, 0, sizeof(unsigned int), stream);            // reset each call
    fused_kernel<<<256, 512, 0, stream>>>(features, landmarks, W_lin, b_lin,
                                          pooled, bar, out);
}